// Round 7
// baseline (418.238 us; speedup 1.0000x reference)
//
#include <hip/hip_runtime.h>
#include <math.h>

// ---------------------------------------------------------------------------
// ImplicitFlowDecoder — R15:
//  - 8-wave blocks (512 thr), MP=64 unchanged: all layers MT=1 (acc <= 32
//    AGPR), M-tiles spread across 8 waves -> combined regs ~80 ->
//    __launch_bounds__(512,6) gives 3 blocks/CU = 24 waves/CU (+50% occ).
//  - pf A-prefetch dropped (R14 proved null; saves 16-32 VGPR).
//  - H2 (M=64) on waves 0-3 via active guard; barriers stay uniform.
// R13: W2@Wp fused; EP5 in-reg f16 residual; pre-sig gates. R12: [HW][C] bf16
// maps + uint4 gathers. R11: lgkm-only barriers. R10: constexpr prep, H0
// K=272, exp2 gelu, setprio.
// ---------------------------------------------------------------------------

typedef short bf16x8 __attribute__((ext_vector_type(8)));
typedef float f32x16 __attribute__((ext_vector_type(16)));

constexpr int W8 = 64, H8 = 48, W16g = 32, H16g = 24, WF_ = 512, HF = 384;
constexpr int HWs8 = W8 * H8;      // 3072
constexpr int HWs16 = W16g * H16g; // 768
constexpr int MP = 64;
constexpr int NTH = 512;
constexpr int BPR = WF_ / MP;               // 8
constexpr int NBLK = 2 * HF * BPR;          // 6144

constexpr int S = 280;      // row stride (ushorts), 8-aligned for b128

// d_ws layout (ushort elems)
constexpr int OFF_WC = 0;
constexpr int OFF_W1 = 8192;
constexpr int OFF_W2 = 40960;    // fused WF (256x128)
constexpr int OFF_WP = 73728;    // unused region (layout stability)
constexpr int OFF_W3 = 90112;
constexpr int OFF_W4 = 122880;
constexpr int OFF_H0 = 155648;   // K padded 260->272
constexpr int OFF_H1 = 225280;
constexpr int OFF_H2 = 258048;
constexpr int SWZ_TOTAL = 266240;
// transposed feature maps, bf16 [B][HW][C]
constexpr int OFF_T   = SWZ_TOTAL;                 // feat1   [2][3072][128]
constexpr int OFF_T8  = OFF_T  + 2 * HWs8 * 128;   // feat_s8 [2][3072][128]
constexpr int OFF_TC  = OFF_T8 + 2 * HWs8 * 128;   // ctx     [2][3072][64]
constexpr int OFF_T16 = OFF_TC + 2 * HWs8 * 64;    // feat_s16[2][768][128]
// small f32 tables
constexpr int OFF_BF  = OFF_T16 + 2 * HWs16 * 128;
constexpr int OFF_G1S = OFF_BF + 256;
constexpr int OFF_G2S = OFF_G1S + 256;

__device__ __forceinline__ unsigned short f2bf(float f) {  // RNE (prep only)
  union { float f; unsigned u; } v; v.f = f;
  unsigned r = (v.u + 0x7fffu + ((v.u >> 16) & 1u)) >> 16;
  return (unsigned short)r;
}
__device__ __forceinline__ float bflo(unsigned u) {
  return __builtin_bit_cast(float, u << 16);
}
__device__ __forceinline__ float bfhi(unsigned u) {
  return __builtin_bit_cast(float, u & 0xffff0000u);
}
#if defined(__has_builtin)
#if __has_builtin(__builtin_amdgcn_cvt_pk_bf16_f32)
#define HAS_PK_BF16 1
#endif
#if __has_builtin(__builtin_amdgcn_exp2f)
#define HAS_EXP2 1
#endif
#endif
__device__ __forceinline__ unsigned pack2bf(float a, float b) {
#ifdef HAS_PK_BF16
  typedef __bf16 bf2_t __attribute__((ext_vector_type(2)));
  bf2_t r = __builtin_amdgcn_cvt_pk_bf16_f32(a, b);
  return __builtin_bit_cast(unsigned, r);
#else
  unsigned ua = __builtin_bit_cast(unsigned, a) + 0x8000u;
  unsigned ub = __builtin_bit_cast(unsigned, b) + 0x8000u;
  return __builtin_amdgcn_perm(ub, ua, 0x07060302u);
#endif
}
__device__ __forceinline__ float exp2_fast(float x) {
#ifdef HAS_EXP2
  return __builtin_amdgcn_exp2f(x);
#else
  float r;
  asm("v_exp_f32 %0, %1" : "=v"(r) : "v"(x));
  return r;
#endif
}
// tanh-GELU in sigmoid form with log2e pre-folded
__device__ __forceinline__ float gelu_fast(float x) {
  float t = fmaf(x * x, -0.10294433f, -2.3022082f);
  float e = exp2_fast(x * t);
  return x * __builtin_amdgcn_rcpf(1.0f + e);
}

// LDS-only barrier: no vmcnt(0) drain (no cross-thread global deps in-kernel).
__device__ __forceinline__ void barrier_lds() {
  asm volatile("s_waitcnt lgkmcnt(0)" ::: "memory");
  __builtin_amdgcn_s_barrier();
  asm volatile("" ::: "memory");
}

// ------------------------------- prep kernel -------------------------------
struct PrepParams {
  const float* W[9];
  const float* f1; const float* f8; const float* ctx; const float* f16;
  const float* b2; const float* bp; const float* g1; const float* g2;
  unsigned short* ws;
};

constexpr int PTH = 256;
constexpr int PREP_W_BLOCKS = SWZ_TOTAL / PTH;   // 1040
constexpr int HWT = 32;
constexpr int TB_F1 = 2 * (HWs8 / HWT);
constexpr int TB_F8 = TB_F1;
constexpr int TB_CTX = TB_F1;
constexpr int TB_F16 = 2 * (HWs16 / HWT);
constexpr int PREP_T_BLOCKS = TB_F1 + TB_F8 + TB_CTX + TB_F16;  // 624

template<int KK, int KP, int NN>
__device__ __forceinline__ void prep_one(const float* __restrict__ W,
                                         unsigned short* __restrict__ dst, int q) {
  int j = q & 7;
  int l = (q >> 3) & 63;
  int r = q >> 9;
  constexpr int nks = KP >> 4;
  int ks = r % nks;
  int mt = r / nks;
  int n = mt * 32 + (l & 31);
  int k = ks * 16 + ((l >> 5) << 3) + j;
  float v = (k < KK) ? W[k * NN + n] : 0.0f;
  dst[q] = f2bf(v);
}

// fused WF[k][n] = sum_j W2[k][j] * Wp[j][n]   (K=256, N=128), fp32 accumulate
__device__ __forceinline__ void prep_fused(const float* __restrict__ W2,
                                           const float* __restrict__ Wp,
                                           unsigned short* __restrict__ dst, int q) {
  int j = q & 7;
  int l = (q >> 3) & 63;
  int r = q >> 9;
  constexpr int nks = 16;
  int ks = r % nks;
  int mt = r / nks;
  int n = mt * 32 + (l & 31);
  int k = ks * 16 + ((l >> 5) << 3) + j;
  float v = 0.0f;
  for (int jj = 0; jj < 128; ++jj)
    v = fmaf(W2[k * 128 + jj], Wp[jj * 128 + n], v);
  dst[q] = f2bf(v);
}

template<int C>
__device__ __forceinline__ void transpose_fm(const float* __restrict__ src,
    unsigned short* __restrict__ dst, int HWtot, int hw0,
    unsigned short* __restrict__ tile)
{
  const int t = threadIdx.x;
  const int hw = t & (HWT - 1);
  const int cg = t >> 5;
#pragma unroll
  for (int c0 = 0; c0 < C / 8; ++c0) {
    int c = c0 * 8 + cg;
    tile[c * (HWT + 2) + hw] = f2bf(src[(size_t)c * HWtot + hw0 + hw]);
  }
  __syncthreads();
  constexpr int CD = C / 2;
  constexpr int RP = 256 / CD;
  const int cD = t & (CD - 1);
  const int hg = t / CD;
#pragma unroll
  for (int h0 = 0; h0 < HWT / RP; ++h0) {
    int hh = h0 * RP + hg;
    unsigned lo = tile[(2 * cD) * (HWT + 2) + hh];
    unsigned hi = tile[(2 * cD + 1) * (HWT + 2) + hh];
    *(unsigned*)(dst + (size_t)(hw0 + hh) * C + 2 * cD) = lo | (hi << 16);
  }
}

__global__ void prep_kernel(PrepParams pp) {
  __shared__ unsigned short tile[128 * (HWT + 2)];
  const int blk = blockIdx.x;
  if (blk < PREP_W_BLOCKS) {
    int e = blk * PTH + threadIdx.x;
    unsigned short* ws = pp.ws;
    if (e < OFF_W1)      prep_one<64, 64, 128>(pp.W[0], ws + OFF_WC, e - OFF_WC);
    else if (e < OFF_W2) prep_one<128, 128, 256>(pp.W[1], ws + OFF_W1, e - OFF_W1);
    else if (e < OFF_WP) prep_fused(pp.W[2], pp.W[3], ws + OFF_W2, e - OFF_W2);
    else if (e < OFF_W3) { /* unused */ }
    else if (e < OFF_W4) prep_one<128, 128, 256>(pp.W[4], ws + OFF_W3, e - OFF_W3);
    else if (e < OFF_H0) prep_one<256, 256, 128>(pp.W[5], ws + OFF_W4, e - OFF_W4);
    else if (e < OFF_H1) prep_one<260, 272, 256>(pp.W[6], ws + OFF_H0, e - OFF_H0);
    else if (e < OFF_H2) prep_one<256, 256, 128>(pp.W[7], ws + OFF_H1, e - OFF_H1);
    else                 prep_one<128, 128, 64>(pp.W[8], ws + OFF_H2, e - OFF_H2);
  } else if (blk < PREP_W_BLOCKS + PREP_T_BLOCKS) {
    int tb = blk - PREP_W_BLOCKS;
    if (tb < TB_F1) {
      int b = tb / (HWs8 / HWT), hw0 = (tb % (HWs8 / HWT)) * HWT;
      transpose_fm<128>(pp.f1 + (size_t)b * 128 * HWs8,
                        pp.ws + OFF_T + (size_t)b * HWs8 * 128, HWs8, hw0, tile);
    } else if (tb < TB_F1 + TB_F8) {
      tb -= TB_F1;
      int b = tb / (HWs8 / HWT), hw0 = (tb % (HWs8 / HWT)) * HWT;
      transpose_fm<128>(pp.f8 + (size_t)b * 128 * HWs8,
                        pp.ws + OFF_T8 + (size_t)b * HWs8 * 128, HWs8, hw0, tile);
    } else if (tb < TB_F1 + TB_F8 + TB_CTX) {
      tb -= TB_F1 + TB_F8;
      int b = tb / (HWs8 / HWT), hw0 = (tb % (HWs8 / HWT)) * HWT;
      transpose_fm<64>(pp.ctx + (size_t)b * 64 * HWs8,
                       pp.ws + OFF_TC + (size_t)b * HWs8 * 64, HWs8, hw0, tile);
    } else {
      tb -= TB_F1 + TB_F8 + TB_CTX;
      int b = tb / (HWs16 / HWT), hw0 = (tb % (HWs16 / HWT)) * HWT;
      transpose_fm<128>(pp.f16 + (size_t)b * 128 * HWs16,
                        pp.ws + OFF_T16 + (size_t)b * HWs16 * 128, HWs16, hw0, tile);
    }
  } else {
    int t = threadIdx.x;
    if (t < 128) {
      float acc = pp.bp[t];
      for (int j = 0; j < 128; ++j) acc = fmaf(pp.b2[j], pp.W[3][j * 128 + t], acc);
      ((float*)(pp.ws + OFF_BF))[t] = acc;
    } else {
      int i = t - 128;
      float a = pp.g1[i], b = pp.g2[i];
      ((float*)(pp.ws + OFF_G1S))[i] =
          __builtin_amdgcn_rcpf(1.0f + exp2_fast(a * -1.44269504f));
      ((float*)(pp.ws + OFF_G2S))[i] =
          __builtin_amdgcn_rcpf(1.0f + exp2_fast(b * -1.44269504f));
    }
  }
}

// ------------------------------ main kernel --------------------------------
struct Params {
  const float* coarse;
  const float* bc; const float* b1; const float* b3; const float* b4;
  const float* h0b; const float* h1b; const float* h2b;
  const float* h3w; const float* h3b;
  const unsigned short* ws;
  const unsigned short* wsT;   // feat1 T
  const unsigned short* wsT8;  // feat_s8 T
  const unsigned short* wsTC;  // ctx T
  const unsigned short* wsT16; // feat_s16 T
  const float* bF; const float* g1s; const float* g2s;
  float* out;
};

__device__ __forceinline__ void bilin_setup(float g, int Sg, int& i0, int& i1, float& w) {
  float s = (g + 1.0f) * (0.5f * Sg) - 0.5f;
  float f = floorf(s);
  w = s - f;
  int a = (int)f;
  i0 = min(max(a, 0), Sg - 1);
  i1 = min(max(a + 1, 0), Sg - 1);
}

// 32x32x16 MFMA layer, 8-wave decomposition, MT=1 per wave.
// NTM = number of 32-wide M tiles (M/32). NT==2 -> wave wv owns mt0=wv, both
// point halves (requires NTM==8). NT==1 -> mt0=wv>>1, ntb=wv&1; waves with
// mt0>=NTM are inactive (still hit the uniform barrier).
// EP: 0 none, 1 gelu, 2 relu, 3 gated+residual(LDS), 5 gated+residual(in-reg)
template<int NTM, int NT, int EP, bool SYNC, int K>
__device__ __forceinline__ void mfma_layer(
    const unsigned short* __restrict__ Wsw,
    const float* __restrict__ bias,
    const unsigned short* actIn,
    unsigned short* actOut,
    const float* __restrict__ gate,
    const unsigned short* res,
    const unsigned short* __restrict__ resT = nullptr,
    const int* ro0 = nullptr, const int* ro1 = nullptr,
    const float* rwx = nullptr, const float* rwy = nullptr)
{
  const int t = threadIdx.x;
  const int l = t & 63;
  const int wv = t >> 6;                 // 0..7
  constexpr int nks = K >> 4;
  const int mt0 = (NT == 2) ? wv : (wv >> 1);
  const int ntb = (NT == 2) ? 0 : (wv & 1);
  const bool active = (NT == 2) ? true : (mt0 < NTM);
  const int lh = l >> 5;
  const int ll = l & 31;

  f32x16 acc[NT];
  if (active) {
#pragma unroll
    for (int g = 0; g < 4; ++g) {
      const int f0 = mt0 * 32 + g * 8 + (lh << 2);
      const float4 bv = *(const float4*)(bias + f0);
#pragma unroll
      for (int nt = 0; nt < NT; ++nt) {
        acc[nt][g * 4 + 0] = bv.x; acc[nt][g * 4 + 1] = bv.y;
        acc[nt][g * 4 + 2] = bv.z; acc[nt][g * 4 + 3] = bv.w;
      }
    }
    const unsigned short* bbase = actIn + (ntb * 32 + ll) * S + (lh << 3);
    const unsigned short* abase = Wsw + (size_t)mt0 * nks * 512 + l * 8;

    __builtin_amdgcn_s_setprio(1);
#pragma unroll
    for (int ks = 0; ks < nks; ++ks) {
      bf16x8 B[NT];
#pragma unroll
      for (int nt = 0; nt < NT; ++nt)
        B[nt] = *(const bf16x8*)(bbase + nt * 32 * S + ks * 16);
      bf16x8 A = *(const bf16x8*)(abase + (size_t)ks * 512);
#pragma unroll
      for (int nt = 0; nt < NT; ++nt)
        acc[nt] = __builtin_amdgcn_mfma_f32_32x32x16_bf16(A, B[nt], acc[nt], 0, 0, 0);
    }
    __builtin_amdgcn_s_setprio(0);
  }

  if (SYNC) barrier_lds();

  if (active) {
    // EP5: hoist per-nt residual tap geometry
    float rw00[NT], rw01[NT], rw10[NT], rw11[NT];
    int ro0v[NT], ro1v[NT], rduv[NT];
    if (EP == 5) {
#pragma unroll
      for (int nt = 0; nt < NT; ++nt) {
        const int pt = (ntb + nt) * 32 + ll;
        int e0 = ro0[pt], e1 = ro1[pt];
        float wx = rwx[pt], wy = rwy[pt];
        float w11 = wx * wy;
        rw11[nt] = w11; rw01[nt] = wx - w11; rw10[nt] = wy - w11;
        rw00[nt] = 1.0f - wx - wy + w11;
        rduv[nt] = (e0 & 1) * 128;
        ro0v[nt] = (e0 >> 1) * 128;
        ro1v[nt] = (e1 >> 1) * 128;
      }
    }
#pragma unroll
    for (int g = 0; g < 4; ++g) {
      const int f0 = mt0 * 32 + g * 8 + (lh << 2);
      float4 gv;
      if (EP == 3 || EP == 5) gv = *(const float4*)(gate + f0);  // pre-sigmoided
#pragma unroll
      for (int nt = 0; nt < NT; ++nt) {
        const int pt = (ntb + nt) * 32 + ll;
        float v[4];
        v[0] = acc[nt][g * 4 + 0]; v[1] = acc[nt][g * 4 + 1];
        v[2] = acc[nt][g * 4 + 2]; v[3] = acc[nt][g * 4 + 3];
        if (EP == 1) {
#pragma unroll
          for (int r = 0; r < 4; ++r) v[r] = gelu_fast(v[r]);
        } else if (EP == 2) {
#pragma unroll
          for (int r = 0; r < 4; ++r) v[r] = fmaxf(v[r], 0.0f);
        } else if (EP == 3) {
          uint2 rv = *(const uint2*)(res + pt * S + f0);
          v[0] = fmaf(gv.x, v[0], bflo(rv.x));
          v[1] = fmaf(gv.y, v[1], bfhi(rv.x));
          v[2] = fmaf(gv.z, v[2], bflo(rv.y));
          v[3] = fmaf(gv.w, v[3], bfhi(rv.y));
        } else if (EP == 5) {
          uint2 a00 = *(const uint2*)(resT + ro0v[nt] + f0);
          uint2 a01 = *(const uint2*)(resT + ro0v[nt] + rduv[nt] + f0);
          uint2 a10 = *(const uint2*)(resT + ro1v[nt] + f0);
          uint2 a11 = *(const uint2*)(resT + ro1v[nt] + rduv[nt] + f0);
          float r0 = rw00[nt] * bflo(a00.x) + rw01[nt] * bflo(a01.x)
                   + rw10[nt] * bflo(a10.x) + rw11[nt] * bflo(a11.x);
          float r1 = rw00[nt] * bfhi(a00.x) + rw01[nt] * bfhi(a01.x)
                   + rw10[nt] * bfhi(a10.x) + rw11[nt] * bfhi(a11.x);
          float r2 = rw00[nt] * bflo(a00.y) + rw01[nt] * bflo(a01.y)
                   + rw10[nt] * bflo(a10.y) + rw11[nt] * bflo(a11.y);
          float r3 = rw00[nt] * bfhi(a00.y) + rw01[nt] * bfhi(a01.y)
                   + rw10[nt] * bfhi(a10.y) + rw11[nt] * bfhi(a11.y);
          v[0] = fmaf(gv.x, v[0], r0);
          v[1] = fmaf(gv.y, v[1], r1);
          v[2] = fmaf(gv.z, v[2], r2);
          v[3] = fmaf(gv.w, v[3], r3);
        }
        uint2 pk;
        pk.x = pack2bf(v[0], v[1]);
        pk.y = pack2bf(v[2], v[3]);
        *(uint2*)(actOut + pt * S + f0) = pk;
      }
    }
  }
}

// 4-tap bilinear gather from transposed bf16 [HW][CH] map; 8 channels per item
template<int CH>
__device__ void gather_bilin(const unsigned short* __restrict__ T,
    const int* offA, const int* offB, const float* wxA, const float* wyA,
    unsigned short* outBuf, int colOff)
{
  constexpr int IPP = CH / 8;
  for (int it = threadIdx.x; it < MP * IPP; it += NTH) {
    int pt = it / IPP;
    int c8 = (it & (IPP - 1)) * 8;
    int e0 = offA[pt], e1 = offB[pt];
    int du = (e0 & 1) * CH;
    int o0 = (e0 >> 1) * CH + c8;
    int o1 = (e1 >> 1) * CH + c8;
    float wx = wxA[pt], wy = wyA[pt];
    uint4 a00 = *(const uint4*)(T + o0);
    uint4 a01 = *(const uint4*)(T + o0 + du);
    uint4 a10 = *(const uint4*)(T + o1);
    uint4 a11 = *(const uint4*)(T + o1 + du);
    float w11 = wx * wy;
    float w01 = wx - w11, w10 = wy - w11, w00 = 1.0f - wx - wy + w11;
    uint4 res;
    const unsigned* p00 = (const unsigned*)&a00;
    const unsigned* p01 = (const unsigned*)&a01;
    const unsigned* p10 = (const unsigned*)&a10;
    const unsigned* p11 = (const unsigned*)&a11;
    unsigned* pr = (unsigned*)&res;
#pragma unroll
    for (int q = 0; q < 4; ++q) {
      float r0 = w00 * bflo(p00[q]) + w01 * bflo(p01[q])
               + w10 * bflo(p10[q]) + w11 * bflo(p11[q]);
      float r1 = w00 * bfhi(p00[q]) + w01 * bfhi(p01[q])
               + w10 * bfhi(p10[q]) + w11 * bfhi(p11[q]);
      pr[q] = pack2bf(r0, r1);
    }
    *(uint4*)(outBuf + pt * S + colOff + c8) = res;
  }
}

__global__ __launch_bounds__(512, 6)
void ifd_kernel(Params p)
{
  __shared__ __align__(16) unsigned short buf[MP * S];   // 35840 B
  __shared__ int off8_0[MP], off8_1[MP];
  __shared__ int of16_0[MP], of16_1[MP];
  __shared__ int offT0[MP], offT1[MP];
  __shared__ float w8x[MP], w8y[MP], w16x[MP], w16y[MP], wWx[MP], wWy[MP];
  __shared__ float caxA[MP], cayA[MP];

  const int blk = blockIdx.x;
  const int bb = blk / (HF * BPR);
  const int r = blk % (HF * BPR);
  const int y = r >> 3;
  const int xb = (r & (BPR - 1)) * MP;
  const int t = threadIdx.x;
  const int i = t & 63;          // point
  const int tg = t >> 6;         // wave index / tap group
  const float lim = 1.0f - 1e-6f;

  // ---- phase A (waves 0-3): geometry + one coarse-flow tap per group ----
  if (tg < 4) {
    const int x = xb + i;
    float gx = (x + 0.5f) * (2.0f / WF_) - 1.0f;
    float gy = (y + 0.5f) * (2.0f / HF) - 1.0f;
    gx = fminf(fmaxf(gx, -lim), lim);
    gy = fminf(fmaxf(gy, -lim), lim);

    int x0, x1, y0, y1; float wx, wy;
    bilin_setup(gx, W8, x0, x1, wx);
    bilin_setup(gy, H8, y0, y1, wy);
    if (tg == 0) {
      w8x[i] = wx; w8y[i] = wy;
      int du8 = x1 - x0;
      off8_0[i] = ((y0 * W8 + x0) << 1) | du8;
      off8_1[i] = ((y1 * W8 + x0) << 1) | du8;
      int a0, a1, b0i, b1i; float vx, vy;
      bilin_setup(gx, W16g, a0, a1, vx);
      bilin_setup(gy, H16g, b0i, b1i, vy);
      w16x[i] = vx; w16y[i] = vy;
      int du16 = a1 - a0;
      of16_0[i] = ((b0i * W16g + a0) << 1) | du16;
      of16_1[i] = ((b1i * W16g + a0) << 1) | du16;
    }
    // this group's tap: tg = (ty<<1)|tx
    int xt = (tg & 1) ? x1 : x0;
    int yt = (tg >> 1) ? y1 : y0;
    float wt = ((tg & 1) ? wx : 1.0f - wx) * ((tg >> 1) ? wy : 1.0f - wy);
    const float* cf = p.coarse + bb * 2 * HWs8;
    int o = yt * W8 + xt;
    float px = wt * cf[o];
    float py = wt * cf[HWs8 + o];
    // partials in buf dead cols [64:80) (f32 view): 8 floats per point row
    float* fp = (float*)(buf + i * S + 64);
    fp[tg * 2 + 0] = px;
    fp[tg * 2 + 1] = py;
  }
  barrier_lds();

  // ---- phase B: t<64 combine taps + warp offsets + extras (overlaps gathers)
  if (t < MP) {
    const float* fp = (const float*)(buf + i * S + 64);
    float cfx = (fp[0] + fp[2]) + (fp[4] + fp[6]);
    float cfy = (fp[1] + fp[3]) + (fp[5] + fp[7]);
    float cax = cfx * 8.0f, cay = cfy * 8.0f;
    caxA[i] = cax; cayA[i] = cay;

    const int x = xb + i;
    float gx = fminf(fmaxf((x + 0.5f) * (2.0f / WF_) - 1.0f, -lim), lim);
    float gy = fminf(fmaxf((y + 0.5f) * (2.0f / HF) - 1.0f, -lim), lim);
    float wxn = fminf(fmaxf(gx + cax * (2.0f / WF_), -lim), lim);
    float wyn = fminf(fmaxf(gy + cay * (2.0f / HF), -lim), lim);
    int u0, u1, v0, v1; float uw, vw;
    bilin_setup(wxn, W8, u0, u1, uw);
    bilin_setup(wyn, H8, v0, v1, vw);
    int duW = u1 - u0;
    offT0[i] = ((v0 * W8 + u0) << 1) | duW;
    offT1[i] = ((v1 * W8 + u0) << 1) | duW;
    wWx[i] = uw; wWy[i] = vw;

    // extras cols [256:272): gx,gy | cnx,cny | zeros
    uint4 e0; e0.x = pack2bf(gx, gy);
    e0.y = pack2bf(cax * (1.0f / WF_), cay * (1.0f / HF));
    e0.z = 0; e0.w = 0;
    *(uint4*)(buf + i * S + 256) = e0;
    uint4 ez; ez.x = 0; ez.y = 0; ez.z = 0; ez.w = 0;
    *(uint4*)(buf + i * S + 264) = ez;
  }

  // gathers: f8 -> [128:256) (Wc residual), ctx -> [0:64) (Wc B)
  gather_bilin<128>(p.wsT8 + (size_t)bb * HWs8 * 128, off8_0, off8_1, w8x, w8y, buf, 128);
  gather_bilin<64>(p.wsTC + (size_t)bb * HWs8 * 64, off8_0, off8_1, w8x, w8y, buf, 0);
  barrier_lds();

  // Wc: [0:64) K=64 -> [128:256), res f8 (LDS), gate table g1s
  mfma_layer<4, 1, 3, false, 64>(p.ws + OFF_WC, p.bc, buf, buf + 128, p.g1s, buf + 128);
  barrier_lds();
  // W1: [128:256) K=128 -> [0:256), gelu
  mfma_layer<8, 2, 1, true, 128>(p.ws + OFF_W1, p.b1, buf + 128, buf, nullptr, nullptr);
  barrier_lds();
  // WF (fused W2@Wp): [0:256) K=256 -> [128:256), res f16 in-register, gate g2s
  mfma_layer<4, 1, 5, true, 256>(p.ws + OFF_W2, p.bF, buf, buf + 128, p.g2s, nullptr,
                                 p.wsT16 + (size_t)bb * HWs16 * 128,
                                 of16_0, of16_1, w16x, w16y);
  barrier_lds();
  // W3: [128:256) K=128 -> [0:256), gelu
  mfma_layer<8, 2, 1, true, 128>(p.ws + OFF_W3, p.b3, buf + 128, buf, nullptr, nullptr);
  barrier_lds();
  // W4: [0:256) K=256 -> [0:128); f1 gather -> [128:256)
  mfma_layer<4, 1, 0, true, 256>(p.ws + OFF_W4, p.b4, buf, buf, nullptr, nullptr);
  gather_bilin<128>(p.wsT + (size_t)bb * HWs8 * 128, offT0, offT1, wWx, wWy, buf, 128);
  barrier_lds();
  // flow head, all in-place (H0 K padded 260 -> 272)
  mfma_layer<8, 2, 2, true, 272>(p.ws + OFF_H0, p.h0b, buf, buf, nullptr, nullptr);
  barrier_lds();
  mfma_layer<4, 1, 2, true, 256>(p.ws + OFF_H1, p.h1b, buf, buf, nullptr, nullptr);
  barrier_lds();
  // H2: M=64 -> waves 0-3 active (uniform barrier inside via SYNC)
  mfma_layer<2, 1, 2, true, 128>(p.ws + OFF_H2, p.h2b, buf, buf, nullptr, nullptr);
  barrier_lds();

  // final 64->2 + output (fp32)
  if (t < 128) {
    int ii = t & 63, comp = t >> 6;
    float acc = p.h3b[comp];
    const unsigned short* rowp = buf + ii * S;
    const float* wp = p.h3w + comp;
#pragma unroll
    for (int k8 = 0; k8 < 8; ++k8) {
      uint4 av = *(const uint4*)(rowp + k8 * 8);
      const float* w8p = wp + k8 * 16;
      acc = fmaf(bflo(av.x), w8p[0], acc);
      acc = fmaf(bfhi(av.x), w8p[2], acc);
      acc = fmaf(bflo(av.y), w8p[4], acc);
      acc = fmaf(bfhi(av.y), w8p[6], acc);
      acc = fmaf(bflo(av.z), w8p[8], acc);
      acc = fmaf(bfhi(av.z), w8p[10], acc);
      acc = fmaf(bflo(av.w), w8p[12], acc);
      acc = fmaf(bfhi(av.w), w8p[14], acc);
    }
    float flow = (comp ? cayA[ii] : caxA[ii]) + acc * (comp ? (float)HF : (float)WF_);
    p.out[((bb * 2 + comp) * HF + y) * WF_ + xb + ii] = flow;
  }
}

extern "C" void kernel_launch(void* const* d_in, const int* in_sizes, int n_in,
                              void* d_out, int out_size, void* d_ws, size_t ws_size,
                              hipStream_t stream) {
  PrepParams pp;
  pp.W[0] = (const float*)d_in[6];   // Wc
  pp.W[1] = (const float*)d_in[9];   // W1
  pp.W[2] = (const float*)d_in[11];  // W2 (ffn1_w2) -> fused
  pp.W[3] = (const float*)d_in[13];  // Wp (proj_s8_w) -> fused
  pp.W[4] = (const float*)d_in[16];  // W3
  pp.W[5] = (const float*)d_in[18];  // W4
  pp.W[6] = (const float*)d_in[20];  // hw0
  pp.W[7] = (const float*)d_in[22];  // hw1
  pp.W[8] = (const float*)d_in[24];  // hw2
  pp.f1   = (const float*)d_in[2];
  pp.f8   = (const float*)d_in[1];
  pp.ctx  = (const float*)d_in[4];
  pp.f16  = (const float*)d_in[3];
  pp.b2   = (const float*)d_in[12];
  pp.bp   = (const float*)d_in[14];
  pp.g1   = (const float*)d_in[8];
  pp.g2   = (const float*)d_in[15];
  pp.ws = (unsigned short*)d_ws;
  hipLaunchKernelGGL(prep_kernel, dim3(PREP_W_BLOCKS + PREP_T_BLOCKS + 1), dim3(PTH),
                     0, stream, pp);

  Params p;
  p.coarse = (const float*)d_in[5];
  p.bc  = (const float*)d_in[7];
  p.b1  = (const float*)d_in[10];
  p.b3  = (const float*)d_in[17];
  p.b4  = (const float*)d_in[19];
  p.h0b = (const float*)d_in[21];
  p.h1b = (const float*)d_in[23];
  p.h2b = (const float*)d_in[25];
  p.h3w = (const float*)d_in[26];
  p.h3b = (const float*)d_in[27];
  p.ws   = (const unsigned short*)d_ws;
  p.wsT  = (const unsigned short*)d_ws + OFF_T;
  p.wsT8 = (const unsigned short*)d_ws + OFF_T8;
  p.wsTC = (const unsigned short*)d_ws + OFF_TC;
  p.wsT16= (const unsigned short*)d_ws + OFF_T16;
  p.bF   = (const float*)((const unsigned short*)d_ws + OFF_BF);
  p.g1s  = (const float*)((const unsigned short*)d_ws + OFF_G1S);
  p.g2s  = (const float*)((const unsigned short*)d_ws + OFF_G2S);
  p.out = (float*)d_out;

  hipLaunchKernelGGL(ifd_kernel, dim3(NBLK), dim3(NTH), 0, stream, p);
}

// Round 8
// 390.245 us; speedup vs baseline: 1.0717x; 1.0717x over previous
//
#include <hip/hip_runtime.h>
#include <math.h>

// ---------------------------------------------------------------------------
// ImplicitFlowDecoder — R16 (revert R15's 8-wave regression; back to R14b
// 4-wave structure) + Wc folded into W1:
//  - ALGEBRAIC FOLD: h1@W1 = f8@W1 + fctx@(Wc·diag(sig g1)·W1) + (bc∘s1)@W1
//    -> K-concat [fctx(64)|f8(128)] into one K=192 layer W1cat (prep, fp32).
//    Deletes the Wc layer: -1 barrier phase, -EP3 epilogue, -h1 round trip,
//    -g1s table; +32 MFMA ops/block (+3%). h1 no longer bf16-rounded.
//  - tap partials moved to dead cols [192:208) (f8 B-region now [64:192)).
// R14: pf[8]/pf[4] A-prefetch, parallel setup, extras as uint4.
// R13: W2@Wp fused (EP5 in-reg f16 residual, pre-sig gates). R12: [HW][C]
// bf16 maps + uint4 gathers. R11: lgkm barriers. R10: exp2 gelu, setprio.
// ---------------------------------------------------------------------------

typedef short bf16x8 __attribute__((ext_vector_type(8)));
typedef float f32x16 __attribute__((ext_vector_type(16)));

constexpr int W8 = 64, H8 = 48, W16g = 32, H16g = 24, WF_ = 512, HF = 384;
constexpr int HWs8 = W8 * H8;      // 3072
constexpr int HWs16 = W16g * H16g; // 768
constexpr int MP = 64;
constexpr int NTH = 256;
constexpr int BPR = WF_ / MP;               // 8
constexpr int NBLK = 2 * HF * BPR;          // 6144

constexpr int S = 280;      // row stride (ushorts), 8-aligned for b128

// d_ws layout (ushort elems)
constexpr int OFF_W1C = 0;        // W1cat 192x256
constexpr int OFF_W2  = 49152;    // fused WF (256x128)
constexpr int OFF_W3  = 81920;    // ffn2_w1 128x256
constexpr int OFF_W4  = 114688;   // ffn2_w2 256x128
constexpr int OFF_H0  = 147456;   // hw0, K padded 260->272
constexpr int OFF_H1  = 217088;   // hw1 256x128
constexpr int OFF_H2  = 249856;   // hw2 128x64
constexpr int SWZ_TOTAL = 258048;
// transposed feature maps, bf16 [B][HW][C]
constexpr int OFF_T   = SWZ_TOTAL;                 // feat1   [2][3072][128]
constexpr int OFF_T8  = OFF_T  + 2 * HWs8 * 128;   // feat_s8 [2][3072][128]
constexpr int OFF_TC  = OFF_T8 + 2 * HWs8 * 128;   // ctx     [2][3072][64]
constexpr int OFF_T16 = OFF_TC + 2 * HWs8 * 64;    // feat_s16[2][768][128]
// small f32 tables (ush units)
constexpr int OFF_BF  = OFF_T16 + 2 * HWs16 * 128; // 128 f32
constexpr int OFF_B1C = OFF_BF + 256;              // 256 f32
constexpr int OFF_G2S = OFF_B1C + 512;             // 128 f32

__device__ __forceinline__ unsigned short f2bf(float f) {  // RNE (prep only)
  union { float f; unsigned u; } v; v.f = f;
  unsigned r = (v.u + 0x7fffu + ((v.u >> 16) & 1u)) >> 16;
  return (unsigned short)r;
}
__device__ __forceinline__ float bflo(unsigned u) {
  return __builtin_bit_cast(float, u << 16);
}
__device__ __forceinline__ float bfhi(unsigned u) {
  return __builtin_bit_cast(float, u & 0xffff0000u);
}
#if defined(__has_builtin)
#if __has_builtin(__builtin_amdgcn_cvt_pk_bf16_f32)
#define HAS_PK_BF16 1
#endif
#if __has_builtin(__builtin_amdgcn_exp2f)
#define HAS_EXP2 1
#endif
#endif
__device__ __forceinline__ unsigned pack2bf(float a, float b) {
#ifdef HAS_PK_BF16
  typedef __bf16 bf2_t __attribute__((ext_vector_type(2)));
  bf2_t r = __builtin_amdgcn_cvt_pk_bf16_f32(a, b);
  return __builtin_bit_cast(unsigned, r);
#else
  unsigned ua = __builtin_bit_cast(unsigned, a) + 0x8000u;
  unsigned ub = __builtin_bit_cast(unsigned, b) + 0x8000u;
  return __builtin_amdgcn_perm(ub, ua, 0x07060302u);
#endif
}
__device__ __forceinline__ float exp2_fast(float x) {
#ifdef HAS_EXP2
  return __builtin_amdgcn_exp2f(x);
#else
  float r;
  asm("v_exp_f32 %0, %1" : "=v"(r) : "v"(x));
  return r;
#endif
}
__device__ __forceinline__ float sigmoid_fast(float x) {
  return __builtin_amdgcn_rcpf(1.0f + exp2_fast(x * -1.44269504f));
}
// tanh-GELU in sigmoid form with log2e pre-folded
__device__ __forceinline__ float gelu_fast(float x) {
  float t = fmaf(x * x, -0.10294433f, -2.3022082f);
  float e = exp2_fast(x * t);
  return x * __builtin_amdgcn_rcpf(1.0f + e);
}

// LDS-only barrier: no vmcnt(0) drain (no cross-thread global deps in-kernel).
__device__ __forceinline__ void barrier_lds() {
  asm volatile("s_waitcnt lgkmcnt(0)" ::: "memory");
  __builtin_amdgcn_s_barrier();
  asm volatile("" ::: "memory");
}

// ------------------------------- prep kernel -------------------------------
struct PrepParams {
  const float* W[9];
  const float* f1; const float* f8; const float* ctx; const float* f16;
  const float* bc; const float* b1; const float* b2; const float* bp;
  const float* g1; const float* g2;
  unsigned short* ws;
};

constexpr int PTH = 256;
constexpr int PREP_W_BLOCKS = SWZ_TOTAL / PTH;   // 1008
constexpr int HWT = 32;
constexpr int TB_F1 = 2 * (HWs8 / HWT);
constexpr int TB_F8 = TB_F1;
constexpr int TB_CTX = TB_F1;
constexpr int TB_F16 = 2 * (HWs16 / HWT);
constexpr int PREP_T_BLOCKS = TB_F1 + TB_F8 + TB_CTX + TB_F16;  // 624

template<int KK, int KP, int NN>
__device__ __forceinline__ void prep_one(const float* __restrict__ W,
                                         unsigned short* __restrict__ dst, int q) {
  int j = q & 7;
  int l = (q >> 3) & 63;
  int r = q >> 9;
  constexpr int nks = KP >> 4;
  int ks = r % nks;
  int mt = r / nks;
  int n = mt * 32 + (l & 31);
  int k = ks * 16 + ((l >> 5) << 3) + j;
  float v = (k < KK) ? W[k * NN + n] : 0.0f;
  dst[q] = f2bf(v);
}

// W1cat: rows [0:64) = Wc @ diag(sig g1) @ W1 ; rows [64:192) = W1. N=256.
__device__ __forceinline__ void prep_w1cat(const float* __restrict__ Wc,
                                           const float* __restrict__ W1,
                                           const float* __restrict__ g1,
                                           unsigned short* __restrict__ dst, int q) {
  int j = q & 7;
  int l = (q >> 3) & 63;
  int r = q >> 9;
  constexpr int nks = 12;   // K=192
  int ks = r % nks;
  int mt = r / nks;
  int n = mt * 32 + (l & 31);
  int k = ks * 16 + ((l >> 5) << 3) + j;
  float v;
  if (k < 64) {
    v = 0.0f;
    for (int jj = 0; jj < 128; ++jj) {
      float s = sigmoid_fast(g1[jj]);
      v = fmaf(Wc[k * 128 + jj] * s, W1[jj * 256 + n], v);
    }
  } else {
    v = W1[(k - 64) * 256 + n];
  }
  dst[q] = f2bf(v);
}

// fused WF[k][n] = sum_j W2[k][j] * Wp[j][n]   (K=256, N=128), fp32 accumulate
__device__ __forceinline__ void prep_fused(const float* __restrict__ W2,
                                           const float* __restrict__ Wp,
                                           unsigned short* __restrict__ dst, int q) {
  int j = q & 7;
  int l = (q >> 3) & 63;
  int r = q >> 9;
  constexpr int nks = 16;
  int ks = r % nks;
  int mt = r / nks;
  int n = mt * 32 + (l & 31);
  int k = ks * 16 + ((l >> 5) << 3) + j;
  float v = 0.0f;
  for (int jj = 0; jj < 128; ++jj)
    v = fmaf(W2[k * 128 + jj], Wp[jj * 128 + n], v);
  dst[q] = f2bf(v);
}

template<int C>
__device__ __forceinline__ void transpose_fm(const float* __restrict__ src,
    unsigned short* __restrict__ dst, int HWtot, int hw0,
    unsigned short* __restrict__ tile)
{
  const int t = threadIdx.x;
  const int hw = t & (HWT - 1);
  const int cg = t >> 5;
#pragma unroll
  for (int c0 = 0; c0 < C / 8; ++c0) {
    int c = c0 * 8 + cg;
    tile[c * (HWT + 2) + hw] = f2bf(src[(size_t)c * HWtot + hw0 + hw]);
  }
  __syncthreads();
  constexpr int CD = C / 2;
  constexpr int RP = 256 / CD;
  const int cD = t & (CD - 1);
  const int hg = t / CD;
#pragma unroll
  for (int h0 = 0; h0 < HWT / RP; ++h0) {
    int hh = h0 * RP + hg;
    unsigned lo = tile[(2 * cD) * (HWT + 2) + hh];
    unsigned hi = tile[(2 * cD + 1) * (HWT + 2) + hh];
    *(unsigned*)(dst + (size_t)(hw0 + hh) * C + 2 * cD) = lo | (hi << 16);
  }
}

__global__ void prep_kernel(PrepParams pp) {
  __shared__ unsigned short tile[128 * (HWT + 2)];
  const int blk = blockIdx.x;
  if (blk < PREP_W_BLOCKS) {
    int e = blk * PTH + threadIdx.x;
    unsigned short* ws = pp.ws;
    if (e < OFF_W2)      prep_w1cat(pp.W[0], pp.W[1], pp.g1, ws + OFF_W1C, e - OFF_W1C);
    else if (e < OFF_W3) prep_fused(pp.W[2], pp.W[3], ws + OFF_W2, e - OFF_W2);
    else if (e < OFF_W4) prep_one<128, 128, 256>(pp.W[4], ws + OFF_W3, e - OFF_W3);
    else if (e < OFF_H0) prep_one<256, 256, 128>(pp.W[5], ws + OFF_W4, e - OFF_W4);
    else if (e < OFF_H1) prep_one<260, 272, 256>(pp.W[6], ws + OFF_H0, e - OFF_H0);
    else if (e < OFF_H2) prep_one<256, 256, 128>(pp.W[7], ws + OFF_H1, e - OFF_H1);
    else                 prep_one<128, 128, 64>(pp.W[8], ws + OFF_H2, e - OFF_H2);
  } else if (blk < PREP_W_BLOCKS + PREP_T_BLOCKS) {
    int tb = blk - PREP_W_BLOCKS;
    if (tb < TB_F1) {
      int b = tb / (HWs8 / HWT), hw0 = (tb % (HWs8 / HWT)) * HWT;
      transpose_fm<128>(pp.f1 + (size_t)b * 128 * HWs8,
                        pp.ws + OFF_T + (size_t)b * HWs8 * 128, HWs8, hw0, tile);
    } else if (tb < TB_F1 + TB_F8) {
      tb -= TB_F1;
      int b = tb / (HWs8 / HWT), hw0 = (tb % (HWs8 / HWT)) * HWT;
      transpose_fm<128>(pp.f8 + (size_t)b * 128 * HWs8,
                        pp.ws + OFF_T8 + (size_t)b * HWs8 * 128, HWs8, hw0, tile);
    } else if (tb < TB_F1 + TB_F8 + TB_CTX) {
      tb -= TB_F1 + TB_F8;
      int b = tb / (HWs8 / HWT), hw0 = (tb % (HWs8 / HWT)) * HWT;
      transpose_fm<64>(pp.ctx + (size_t)b * 64 * HWs8,
                       pp.ws + OFF_TC + (size_t)b * HWs8 * 64, HWs8, hw0, tile);
    } else {
      tb -= TB_F1 + TB_F8 + TB_CTX;
      int b = tb / (HWs16 / HWT), hw0 = (tb % (HWs16 / HWT)) * HWT;
      transpose_fm<128>(pp.f16 + (size_t)b * 128 * HWs16,
                        pp.ws + OFF_T16 + (size_t)b * HWs16 * 128, HWs16, hw0, tile);
    }
  } else {
    // tables: bF [0,128), b1cat [128,384), g2s [384,512)
    for (int idx = threadIdx.x; idx < 512; idx += PTH) {
      if (idx < 128) {
        float acc = pp.bp[idx];
        for (int j = 0; j < 128; ++j)
          acc = fmaf(pp.b2[j], pp.W[3][j * 128 + idx], acc);
        ((float*)(pp.ws + OFF_BF))[idx] = acc;
      } else if (idx < 384) {
        int n = idx - 128;
        float acc = pp.b1[n];
        for (int j = 0; j < 128; ++j)
          acc = fmaf(pp.bc[j] * sigmoid_fast(pp.g1[j]), pp.W[1][j * 256 + n], acc);
        ((float*)(pp.ws + OFF_B1C))[n] = acc;
      } else {
        int n = idx - 384;
        ((float*)(pp.ws + OFF_G2S))[n] = sigmoid_fast(pp.g2[n]);
      }
    }
  }
}

// ------------------------------ main kernel --------------------------------
struct Params {
  const float* coarse;
  const float* b3; const float* b4;
  const float* h0b; const float* h1b; const float* h2b;
  const float* h3w; const float* h3b;
  const unsigned short* ws;
  const unsigned short* wsT;   // feat1 T
  const unsigned short* wsT8;  // feat_s8 T
  const unsigned short* wsTC;  // ctx T
  const unsigned short* wsT16; // feat_s16 T
  const float* bF; const float* b1c; const float* g2s;
  float* out;
};

__device__ __forceinline__ void bilin_setup(float g, int Sg, int& i0, int& i1, float& w) {
  float s = (g + 1.0f) * (0.5f * Sg) - 0.5f;
  float f = floorf(s);
  w = s - f;
  int a = (int)f;
  i0 = min(max(a, 0), Sg - 1);
  i1 = min(max(a + 1, 0), Sg - 1);
}

// prefetch the next layer's first D A-tiles (consumption order: ks-major, m-minor)
template<int MTN, int NTN, int NKSN, int D>
__device__ __forceinline__ void prefetchA(const unsigned short* __restrict__ Wsw,
                                          bf16x8* pf) {
  const int t = threadIdx.x;
  const int l = t & 63;
  const int wv = t >> 6;
  const int mt0 = (NTN == 2) ? wv * MTN : (wv >> 1);
  const unsigned short* ab = Wsw + (size_t)mt0 * NKSN * 512 + l * 8;
#pragma unroll
  for (int idx = 0; idx < D; ++idx) {
    const int ks = (MTN == 2) ? (idx >> 1) : idx;
    const int m  = (MTN == 2) ? (idx & 1) : 0;
    pf[idx] = *(const bf16x8*)(ab + ((size_t)m * NKSN + ks) * 512);
  }
}

// 32x32x16 MFMA layer; bias in accumulator init; first PD A tiles from pf.
// EP: 0 none, 1 gelu, 2 relu, 5 gated+residual(in-reg gather, pre-sig gate)
template<int MT, int NT, int EP, bool SYNC, int K, int PD>
__device__ __forceinline__ void mfma_layer(
    const unsigned short* __restrict__ Wsw,
    const float* __restrict__ bias,
    const unsigned short* actIn,
    unsigned short* actOut,
    const float* __restrict__ gate,
    const bf16x8* pf,
    const unsigned short* __restrict__ resT = nullptr,
    const int* ro0 = nullptr, const int* ro1 = nullptr,
    const float* rwx = nullptr, const float* rwy = nullptr)
{
  const int t = threadIdx.x;
  const int l = t & 63;
  const int wv = t >> 6;
  constexpr int nks = K >> 4;
  const int mt0 = (NT == 2) ? wv * MT : (wv >> 1);
  const int ntb = (NT == 2) ? 0 : (wv & 1);
  const int lh = l >> 5;
  const int ll = l & 31;

  f32x16 acc[MT][NT];
#pragma unroll
  for (int m = 0; m < MT; ++m) {
#pragma unroll
    for (int g = 0; g < 4; ++g) {
      const int f0 = (mt0 + m) * 32 + g * 8 + (lh << 2);
      const float4 bv = *(const float4*)(bias + f0);
#pragma unroll
      for (int nt = 0; nt < NT; ++nt) {
        acc[m][nt][g * 4 + 0] = bv.x; acc[m][nt][g * 4 + 1] = bv.y;
        acc[m][nt][g * 4 + 2] = bv.z; acc[m][nt][g * 4 + 3] = bv.w;
      }
    }
  }

  const unsigned short* bbase = actIn + (ntb * 32 + ll) * S + (lh << 3);
  const unsigned short* abase = Wsw + (size_t)mt0 * nks * 512 + l * 8;

  __builtin_amdgcn_s_setprio(1);
#pragma unroll
  for (int ks = 0; ks < nks; ++ks) {
    bf16x8 B[NT];
#pragma unroll
    for (int nt = 0; nt < NT; ++nt)
      B[nt] = *(const bf16x8*)(bbase + nt * 32 * S + ks * 16);
#pragma unroll
    for (int m = 0; m < MT; ++m) {
      bf16x8 A;
      if (ks * MT + m < PD) A = pf[ks * MT + m];
      else A = *(const bf16x8*)(abase + (m * nks + ks) * 512);
#pragma unroll
      for (int nt = 0; nt < NT; ++nt)
        acc[m][nt] = __builtin_amdgcn_mfma_f32_32x32x16_bf16(A, B[nt], acc[m][nt], 0, 0, 0);
    }
  }
  __builtin_amdgcn_s_setprio(0);

  if (SYNC) barrier_lds();

  // EP5: hoist per-nt residual tap geometry
  float rw00[NT], rw01[NT], rw10[NT], rw11[NT];
  int ro0v[NT], ro1v[NT], rduv[NT];
  if (EP == 5) {
#pragma unroll
    for (int nt = 0; nt < NT; ++nt) {
      const int pt = (ntb + nt) * 32 + ll;
      int e0 = ro0[pt], e1 = ro1[pt];
      float wx = rwx[pt], wy = rwy[pt];
      float w11 = wx * wy;
      rw11[nt] = w11; rw01[nt] = wx - w11; rw10[nt] = wy - w11;
      rw00[nt] = 1.0f - wx - wy + w11;
      rduv[nt] = (e0 & 1) * 128;
      ro0v[nt] = (e0 >> 1) * 128;
      ro1v[nt] = (e1 >> 1) * 128;
    }
  }

#pragma unroll
  for (int m = 0; m < MT; ++m) {
#pragma unroll
    for (int g = 0; g < 4; ++g) {
      const int f0 = (mt0 + m) * 32 + g * 8 + (lh << 2);
      float4 gv;
      if (EP == 5) gv = *(const float4*)(gate + f0);  // pre-sigmoided
#pragma unroll
      for (int nt = 0; nt < NT; ++nt) {
        const int pt = (ntb + nt) * 32 + ll;
        float v[4];
        v[0] = acc[m][nt][g * 4 + 0]; v[1] = acc[m][nt][g * 4 + 1];
        v[2] = acc[m][nt][g * 4 + 2]; v[3] = acc[m][nt][g * 4 + 3];
        if (EP == 1) {
#pragma unroll
          for (int r = 0; r < 4; ++r) v[r] = gelu_fast(v[r]);
        } else if (EP == 2) {
#pragma unroll
          for (int r = 0; r < 4; ++r) v[r] = fmaxf(v[r], 0.0f);
        } else if (EP == 5) {
          uint2 a00 = *(const uint2*)(resT + ro0v[nt] + f0);
          uint2 a01 = *(const uint2*)(resT + ro0v[nt] + rduv[nt] + f0);
          uint2 a10 = *(const uint2*)(resT + ro1v[nt] + f0);
          uint2 a11 = *(const uint2*)(resT + ro1v[nt] + rduv[nt] + f0);
          float r0 = rw00[nt] * bflo(a00.x) + rw01[nt] * bflo(a01.x)
                   + rw10[nt] * bflo(a10.x) + rw11[nt] * bflo(a11.x);
          float r1 = rw00[nt] * bfhi(a00.x) + rw01[nt] * bfhi(a01.x)
                   + rw10[nt] * bfhi(a10.x) + rw11[nt] * bfhi(a11.x);
          float r2 = rw00[nt] * bflo(a00.y) + rw01[nt] * bflo(a01.y)
                   + rw10[nt] * bflo(a10.y) + rw11[nt] * bflo(a11.y);
          float r3 = rw00[nt] * bfhi(a00.y) + rw01[nt] * bfhi(a01.y)
                   + rw10[nt] * bfhi(a10.y) + rw11[nt] * bfhi(a11.y);
          v[0] = fmaf(gv.x, v[0], r0);
          v[1] = fmaf(gv.y, v[1], r1);
          v[2] = fmaf(gv.z, v[2], r2);
          v[3] = fmaf(gv.w, v[3], r3);
        }
        uint2 pk;
        pk.x = pack2bf(v[0], v[1]);
        pk.y = pack2bf(v[2], v[3]);
        *(uint2*)(actOut + pt * S + f0) = pk;
      }
    }
  }
}

// 4-tap bilinear gather from transposed bf16 [HW][CH] map; 8 channels per item
template<int CH>
__device__ void gather_bilin(const unsigned short* __restrict__ T,
    const int* offA, const int* offB, const float* wxA, const float* wyA,
    unsigned short* outBuf, int colOff)
{
  constexpr int IPP = CH / 8;
  for (int it = threadIdx.x; it < MP * IPP; it += NTH) {
    int pt = it / IPP;
    int c8 = (it & (IPP - 1)) * 8;
    int e0 = offA[pt], e1 = offB[pt];
    int du = (e0 & 1) * CH;
    int o0 = (e0 >> 1) * CH + c8;
    int o1 = (e1 >> 1) * CH + c8;
    float wx = wxA[pt], wy = wyA[pt];
    uint4 a00 = *(const uint4*)(T + o0);
    uint4 a01 = *(const uint4*)(T + o0 + du);
    uint4 a10 = *(const uint4*)(T + o1);
    uint4 a11 = *(const uint4*)(T + o1 + du);
    float w11 = wx * wy;
    float w01 = wx - w11, w10 = wy - w11, w00 = 1.0f - wx - wy + w11;
    uint4 res;
    const unsigned* p00 = (const unsigned*)&a00;
    const unsigned* p01 = (const unsigned*)&a01;
    const unsigned* p10 = (const unsigned*)&a10;
    const unsigned* p11 = (const unsigned*)&a11;
    unsigned* pr = (unsigned*)&res;
#pragma unroll
    for (int q = 0; q < 4; ++q) {
      float r0 = w00 * bflo(p00[q]) + w01 * bflo(p01[q])
               + w10 * bflo(p10[q]) + w11 * bflo(p11[q]);
      float r1 = w00 * bfhi(p00[q]) + w01 * bfhi(p01[q])
               + w10 * bfhi(p10[q]) + w11 * bfhi(p11[q]);
      pr[q] = pack2bf(r0, r1);
    }
    *(uint4*)(outBuf + pt * S + colOff + c8) = res;
  }
}

__global__ __launch_bounds__(256, 4)
void ifd_kernel(Params p)
{
  __shared__ __align__(16) unsigned short buf[MP * S];   // 35840 B
  __shared__ int off8_0[MP], off8_1[MP];
  __shared__ int of16_0[MP], of16_1[MP];
  __shared__ int offT0[MP], offT1[MP];
  __shared__ float w8x[MP], w8y[MP], w16x[MP], w16y[MP], wWx[MP], wWy[MP];
  __shared__ float caxA[MP], cayA[MP];

  bf16x8 pf[8];

  const int blk = blockIdx.x;
  const int bb = blk / (HF * BPR);
  const int r = blk % (HF * BPR);
  const int y = r >> 3;
  const int xb = (r & (BPR - 1)) * MP;
  const int t = threadIdx.x;
  const int i = t & 63;          // point
  const int tg = t >> 6;         // tap group
  const float lim = 1.0f - 1e-6f;

  // ---- phase A (all 256 threads): geometry + one coarse-flow tap each ----
  {
    const int x = xb + i;
    float gx = (x + 0.5f) * (2.0f / WF_) - 1.0f;
    float gy = (y + 0.5f) * (2.0f / HF) - 1.0f;
    gx = fminf(fmaxf(gx, -lim), lim);
    gy = fminf(fmaxf(gy, -lim), lim);

    int x0, x1, y0, y1; float wx, wy;
    bilin_setup(gx, W8, x0, x1, wx);
    bilin_setup(gy, H8, y0, y1, wy);
    if (tg == 0) {
      w8x[i] = wx; w8y[i] = wy;
      int du8 = x1 - x0;
      off8_0[i] = ((y0 * W8 + x0) << 1) | du8;
      off8_1[i] = ((y1 * W8 + x0) << 1) | du8;
      int a0, a1, b0i, b1i; float vx, vy;
      bilin_setup(gx, W16g, a0, a1, vx);
      bilin_setup(gy, H16g, b0i, b1i, vy);
      w16x[i] = vx; w16y[i] = vy;
      int du16 = a1 - a0;
      of16_0[i] = ((b0i * W16g + a0) << 1) | du16;
      of16_1[i] = ((b1i * W16g + a0) << 1) | du16;
    }
    // this group's tap: tg = (ty<<1)|tx
    int xt = (tg & 1) ? x1 : x0;
    int yt = (tg >> 1) ? y1 : y0;
    float wt = ((tg & 1) ? wx : 1.0f - wx) * ((tg >> 1) ? wy : 1.0f - wy);
    const float* cf = p.coarse + bb * 2 * HWs8;
    int o = yt * W8 + xt;
    float px = wt * cf[o];
    float py = wt * cf[HWs8 + o];
    // partials in buf dead cols [192:208) (f32 view): 8 floats per point row
    float* fp = (float*)(buf + i * S + 192);
    fp[tg * 2 + 0] = px;
    fp[tg * 2 + 1] = py;
  }
  prefetchA<2, 2, 12, 4>(p.ws + OFF_W1C, pf);
  barrier_lds();

  // ---- phase B: t<64 combine taps + warp offsets + extras (overlaps gathers)
  if (t < MP) {
    const float* fp = (const float*)(buf + i * S + 192);
    float cfx = (fp[0] + fp[2]) + (fp[4] + fp[6]);
    float cfy = (fp[1] + fp[3]) + (fp[5] + fp[7]);
    float cax = cfx * 8.0f, cay = cfy * 8.0f;
    caxA[i] = cax; cayA[i] = cay;

    const int x = xb + i;
    float gx = fminf(fmaxf((x + 0.5f) * (2.0f / WF_) - 1.0f, -lim), lim);
    float gy = fminf(fmaxf((y + 0.5f) * (2.0f / HF) - 1.0f, -lim), lim);
    float wxn = fminf(fmaxf(gx + cax * (2.0f / WF_), -lim), lim);
    float wyn = fminf(fmaxf(gy + cay * (2.0f / HF), -lim), lim);
    int u0, u1, v0, v1; float uw, vw;
    bilin_setup(wxn, W8, u0, u1, uw);
    bilin_setup(wyn, H8, v0, v1, vw);
    int duW = u1 - u0;
    offT0[i] = ((v0 * W8 + u0) << 1) | duW;
    offT1[i] = ((v1 * W8 + u0) << 1) | duW;
    wWx[i] = uw; wWy[i] = vw;

    // extras cols [256:272): gx,gy | cnx,cny | zeros
    uint4 e0; e0.x = pack2bf(gx, gy);
    e0.y = pack2bf(cax * (1.0f / WF_), cay * (1.0f / HF));
    e0.z = 0; e0.w = 0;
    *(uint4*)(buf + i * S + 256) = e0;
    uint4 ez; ez.x = 0; ez.y = 0; ez.z = 0; ez.w = 0;
    *(uint4*)(buf + i * S + 264) = ez;
  }

  // gathers: ctx -> [0:64), f8 -> [64:192)   (K-concat B for W1cat)
  gather_bilin<64>(p.wsTC + (size_t)bb * HWs8 * 64, off8_0, off8_1, w8x, w8y, buf, 0);
  gather_bilin<128>(p.wsT8 + (size_t)bb * HWs8 * 128, off8_0, off8_1, w8x, w8y, buf, 64);
  barrier_lds();

  // W1cat: [0:192) K=192 -> [0:256), gelu  (Wc folded in)
  mfma_layer<2, 2, 1, true, 192, 4>(p.ws + OFF_W1C, p.b1c, buf, buf, nullptr, pf);
  prefetchA<1, 2, 16, 8>(p.ws + OFF_W2, pf);
  barrier_lds();
  // WF (fused W2@Wp): [0:256) K=256 -> [128:256), res f16 in-register, gate g2s
  mfma_layer<1, 2, 5, true, 256, 8>(p.ws + OFF_W2, p.bF, buf, buf + 128, p.g2s, pf,
                                    p.wsT16 + (size_t)bb * HWs16 * 128,
                                    of16_0, of16_1, w16x, w16y);
  prefetchA<2, 2, 8, 4>(p.ws + OFF_W3, pf);
  barrier_lds();
  // W3: [128:256) K=128 -> [0:256), gelu
  mfma_layer<2, 2, 1, true, 128, 4>(p.ws + OFF_W3, p.b3, buf + 128, buf, nullptr, pf);
  prefetchA<1, 2, 16, 8>(p.ws + OFF_W4, pf);
  barrier_lds();
  // W4: [0:256) K=256 -> [0:128); f1 gather -> [128:256)
  mfma_layer<1, 2, 0, true, 256, 8>(p.ws + OFF_W4, p.b4, buf, buf, nullptr, pf);
  gather_bilin<128>(p.wsT + (size_t)bb * HWs8 * 128, offT0, offT1, wWx, wWy, buf, 128);
  prefetchA<2, 2, 17, 4>(p.ws + OFF_H0, pf);
  barrier_lds();
  // flow head, all in-place (H0 K padded 260 -> 272)
  mfma_layer<2, 2, 2, true, 272, 4>(p.ws + OFF_H0, p.h0b, buf, buf, nullptr, pf);
  prefetchA<1, 2, 16, 8>(p.ws + OFF_H1, pf);
  barrier_lds();
  mfma_layer<1, 2, 2, true, 256, 8>(p.ws + OFF_H1, p.h1b, buf, buf, nullptr, pf);
  prefetchA<1, 1, 8, 8>(p.ws + OFF_H2, pf);
  barrier_lds();
  mfma_layer<1, 1, 2, true, 128, 8>(p.ws + OFF_H2, p.h2b, buf, buf, nullptr, pf);
  barrier_lds();

  // final 64->2 + output (fp32)
  if (t < 128) {
    int ii = t & 63, comp = t >> 6;
    float acc = p.h3b[comp];
    const unsigned short* rowp = buf + ii * S;
    const float* wp = p.h3w + comp;
#pragma unroll
    for (int k8 = 0; k8 < 8; ++k8) {
      uint4 av = *(const uint4*)(rowp + k8 * 8);
      const float* w8p = wp + k8 * 16;
      acc = fmaf(bflo(av.x), w8p[0], acc);
      acc = fmaf(bfhi(av.x), w8p[2], acc);
      acc = fmaf(bflo(av.y), w8p[4], acc);
      acc = fmaf(bfhi(av.y), w8p[6], acc);
      acc = fmaf(bflo(av.z), w8p[8], acc);
      acc = fmaf(bfhi(av.z), w8p[10], acc);
      acc = fmaf(bflo(av.w), w8p[12], acc);
      acc = fmaf(bfhi(av.w), w8p[14], acc);
    }
    float flow = (comp ? cayA[ii] : caxA[ii]) + acc * (comp ? (float)HF : (float)WF_);
    p.out[((bb * 2 + comp) * HF + y) * WF_ + xb + ii] = flow;
  }
}

extern "C" void kernel_launch(void* const* d_in, const int* in_sizes, int n_in,
                              void* d_out, int out_size, void* d_ws, size_t ws_size,
                              hipStream_t stream) {
  PrepParams pp;
  pp.W[0] = (const float*)d_in[6];   // Wc (proj_ctx_w)
  pp.W[1] = (const float*)d_in[9];   // W1 (ffn1_w1)
  pp.W[2] = (const float*)d_in[11];  // W2 (ffn1_w2) -> fused WF
  pp.W[3] = (const float*)d_in[13];  // Wp (proj_s8_w) -> fused WF
  pp.W[4] = (const float*)d_in[16];  // W3 (ffn2_w1)
  pp.W[5] = (const float*)d_in[18];  // W4 (ffn2_w2)
  pp.W[6] = (const float*)d_in[20];  // hw0
  pp.W[7] = (const float*)d_in[22];  // hw1
  pp.W[8] = (const float*)d_in[24];  // hw2
  pp.f1   = (const float*)d_in[2];
  pp.f8   = (const float*)d_in[1];
  pp.ctx  = (const float*)d_in[4];
  pp.f16  = (const float*)d_in[3];
  pp.bc   = (const float*)d_in[7];
  pp.b1   = (const float*)d_in[10];
  pp.b2   = (const float*)d_in[12];
  pp.bp   = (const float*)d_in[14];
  pp.g1   = (const float*)d_in[8];
  pp.g2   = (const float*)d_in[15];
  pp.ws = (unsigned short*)d_ws;
  hipLaunchKernelGGL(prep_kernel, dim3(PREP_W_BLOCKS + PREP_T_BLOCKS + 1), dim3(PTH),
                     0, stream, pp);

  Params p;
  p.coarse = (const float*)d_in[5];
  p.b3  = (const float*)d_in[17];
  p.b4  = (const float*)d_in[19];
  p.h0b = (const float*)d_in[21];
  p.h1b = (const float*)d_in[23];
  p.h2b = (const float*)d_in[25];
  p.h3w = (const float*)d_in[26];
  p.h3b = (const float*)d_in[27];
  p.ws   = (const unsigned short*)d_ws;
  p.wsT  = (const unsigned short*)d_ws + OFF_T;
  p.wsT8 = (const unsigned short*)d_ws + OFF_T8;
  p.wsTC = (const unsigned short*)d_ws + OFF_TC;
  p.wsT16= (const unsigned short*)d_ws + OFF_T16;
  p.bF   = (const float*)((const unsigned short*)d_ws + OFF_BF);
  p.b1c  = (const float*)((const unsigned short*)d_ws + OFF_B1C);
  p.g2s  = (const float*)((const unsigned short*)d_ws + OFF_G2S);
  p.out = (float*)d_out;

  hipLaunchKernelGGL(ifd_kernel, dim3(NBLK), dim3(NTH), 0, stream, p);
}